// Round 4
// baseline (570.769 us; speedup 1.0000x reference)
//
#include <hip/hip_runtime.h>
#include <math.h>

#define BATCH 4096
#define D 784
#define N 10000

#define KP 800                 // padded K (halves)
#define BK 32                  // K-step
#define KT (KP / BK)           // 25
#define BM 128
#define BN 128
#define GXMAX 80
#define NPAD (GXMAX * BN)      // 10240
#define MARGIN 3.0f

typedef __attribute__((ext_vector_type(8))) short bh8;
typedef __attribute__((ext_vector_type(4))) float fx4;
typedef const __attribute__((address_space(1))) void CGV;
typedef __attribute__((address_space(3))) void LDSV;

static __device__ __forceinline__ unsigned short f2bf(float f) {
    unsigned u = __float_as_uint(f);
    unsigned r = u + 0x7fffu + ((u >> 16) & 1u);
    return (unsigned short)(r >> 16);
}

static __device__ __forceinline__ void top2_insert(float w, int j, float& v0, int& i0,
                                                   float& v1, int& i1) {
    if (w < v0 || (w == v0 && j < i0)) { v1 = v0; i1 = i0; v0 = w; i0 = j; }
    else if (w < v1 || (w == v1 && j < i1)) { v1 = w; i1 = j; }
}

// ---------------------------------------------------------------------------
__global__ __launch_bounds__(256) void convert_x_kernel(const float* __restrict__ x,
                                                        unsigned short* __restrict__ xh) {
    int row = blockIdx.x;
    const float4* xr = (const float4*)(x + (size_t)row * D);
    unsigned short* dst = xh + (size_t)row * KP;
    for (int i = threadIdx.x; i < KP / 4; i += 256) {
        int k = i * 4;
        uint2 o;
        if (k < D) {
            float4 v = xr[i];
            o.x = (unsigned)f2bf(v.x) | ((unsigned)f2bf(v.y) << 16);
            o.y = (unsigned)f2bf(v.z) | ((unsigned)f2bf(v.w) << 16);
        } else { o.x = 0u; o.y = 0u; }
        *(uint2*)(dst + k) = o;
    }
}

__global__ __launch_bounds__(256) void convert_w_kernel(const float* __restrict__ w,
                                                        unsigned short* __restrict__ wh,
                                                        float* __restrict__ wsq) {
    int row = blockIdx.x;
    unsigned short* dst = wh + (size_t)row * KP;
    float s = 0.f;
    if (row < N) {
        const float4* wr = (const float4*)(w + (size_t)row * D);
        for (int i = threadIdx.x; i < KP / 4; i += 256) {
            int k = i * 4;
            uint2 o;
            if (k < D) {
                float4 v = wr[i];
                s += v.x * v.x + v.y * v.y + v.z * v.z + v.w * v.w;
                o.x = (unsigned)f2bf(v.x) | ((unsigned)f2bf(v.y) << 16);
                o.y = (unsigned)f2bf(v.z) | ((unsigned)f2bf(v.w) << 16);
            } else { o.x = 0u; o.y = 0u; }
            *(uint2*)(dst + k) = o;
        }
    } else {
        for (int i = threadIdx.x; i < KP / 4; i += 256) {
            uint2 o; o.x = 0u; o.y = 0u;
            *(uint2*)(dst + i * 4) = o;
        }
    }
    __shared__ float sred[4];
    #pragma unroll
    for (int off = 32; off; off >>= 1) s += __shfl_down(s, off);
    if ((threadIdx.x & 63) == 0) sred[threadIdx.x >> 6] = s;
    __syncthreads();
    if (threadIdx.x == 0) {
        float t = sred[0] + sred[1] + sred[2] + sred[3];
        wsq[row] = (row < N) ? t : INFINITY;
    }
}

// ---------------------------------------------------------------------------
// MFMA distance kernel. 128x128 tile, 4 waves, double-buffered global_load_lds
// staging, XOR slot-swizzle both-sides, register top-2 per row.
// gx = col-groups (grid.x), cpb = 128-col chunks per block. grid = (gx, 32).
// ---------------------------------------------------------------------------
__global__ __launch_bounds__(256, 4) void dist_mfma_kernel(
    const unsigned short* __restrict__ xh, const unsigned short* __restrict__ wh,
    const float* __restrict__ wsq, float4* __restrict__ partial,
    int gx, int cpb) {
    __shared__ __align__(16) unsigned short As[2][BM * BK];
    __shared__ __align__(16) unsigned short Bs[2][BN * BK];
    __shared__ float4 red[BM][2];

    const int tid = threadIdx.x;
    const int lane = tid & 63;
    const int wid = tid >> 6;
    const int waveM = (wid >> 1) * 64;
    const int waveN = (wid & 1) * 64;

    // XCD-aware remap (nwg = gx*32, nwg%8==0, bijective):
    // XCD x owns rows by in {4x..4x+3}; within an XCD, 4 consecutive slots
    // share the same bx => B-panel L2 reuse, A-panels (4 x 205KB) pinned.
    const int L = blockIdx.x + gx * blockIdx.y;
    const int xcd = L & 7;
    const int s = L >> 3;
    const int bx = s >> 2;               // 0..gx-1
    const int by = xcd * 4 + (s & 3);    // 0..31
    const int rowBase = by * BM;
    const int colBase0 = bx * (cpb * BN);

    // staging: row = j*64 + rr, phys slot = tid&3, logical slot XOR-swizzled
    const int rr = tid >> 2;
    const int csw = (tid & 3) ^ ((rr >> 1) & 3);
    const unsigned short* aSrc0 = xh + (size_t)(rowBase + rr) * KP + csw * 8;
    const unsigned short* aSrc1 = aSrc0 + (size_t)64 * KP;

    char* ldsA0 = (char*)&As[0][0] + wid * 1024;
    char* ldsA1 = (char*)&As[1][0] + wid * 1024;
    char* ldsB0 = (char*)&Bs[0][0] + wid * 1024;
    char* ldsB1 = (char*)&Bs[1][0] + wid * 1024;

    // fragment read offsets (halves), swizzled to match staging
    int offA[4], offB[4];
    #pragma unroll
    for (int m = 0; m < 4; m++) {
        int r = waveM + m * 16 + (lane & 15);
        offA[m] = r * BK + (((lane >> 4) ^ ((r >> 1) & 3)) << 3);
    }
    #pragma unroll
    for (int n = 0; n < 4; n++) {
        int r = waveN + n * 16 + (lane & 15);
        offB[n] = r * BK + (((lane >> 4) ^ ((r >> 1) & 3)) << 3);
    }

    // running per-lane top-2 for 16 (m,r) rows
    float V0[16], V1[16];
    int I0[16], I1[16];
    #pragma unroll
    for (int q = 0; q < 16; q++) {
        V0[q] = INFINITY; V1[q] = INFINITY;
        I0[q] = 0x7fffffff; I1[q] = 0x7fffffff;
    }

#define STAGE(nb, k0)                                                                  \
    do {                                                                               \
        __builtin_amdgcn_global_load_lds((CGV*)(aSrc0 + (k0)), (LDSV*)(ldsA##nb), 16, 0, 0);        \
        __builtin_amdgcn_global_load_lds((CGV*)(aSrc1 + (k0)), (LDSV*)(ldsA##nb + 4096), 16, 0, 0); \
        __builtin_amdgcn_global_load_lds((CGV*)(bSrc0 + (k0)), (LDSV*)(ldsB##nb), 16, 0, 0);        \
        __builtin_amdgcn_global_load_lds((CGV*)(bSrc1 + (k0)), (LDSV*)(ldsB##nb + 4096), 16, 0, 0); \
    } while (0)

#define COMPUTE(nb)                                                                    \
    do {                                                                               \
        bh8 af[4], bf[4];                                                              \
        _Pragma("unroll")                                                              \
        for (int m = 0; m < 4; m++) af[m] = *(const bh8*)&As[nb][offA[m]];             \
        _Pragma("unroll")                                                              \
        for (int n = 0; n < 4; n++) bf[n] = *(const bh8*)&Bs[nb][offB[n]];             \
        _Pragma("unroll")                                                              \
        for (int m = 0; m < 4; m++)                                                    \
            _Pragma("unroll")                                                          \
            for (int n = 0; n < 4; n++)                                                \
                acc[m][n] = __builtin_amdgcn_mfma_f32_16x16x32_bf16(af[m], bf[n],      \
                                                                    acc[m][n], 0, 0, 0); \
    } while (0)

#define VM0 asm volatile("s_waitcnt vmcnt(0)" ::: "memory")
#define BARR __builtin_amdgcn_s_barrier()

    #pragma unroll 1
    for (int c = 0; c < cpb; ++c) {
        const int colBase = colBase0 + c * BN;
        const unsigned short* bSrc0 = wh + (size_t)(colBase + rr) * KP + csw * 8;
        const unsigned short* bSrc1 = bSrc0 + (size_t)64 * KP;

        fx4 acc[4][4];
        #pragma unroll
        for (int m = 0; m < 4; m++)
            #pragma unroll
            for (int n = 0; n < 4; n++) acc[m][n] = (fx4)0.f;

        STAGE(0, 0);
        VM0; BARR;
        #pragma unroll 1
        for (int t = 0; t < KT - 1; t += 2) {   // KT=25 odd: stages tiles 1..24
            STAGE(1, (t + 1) * BK);
            COMPUTE(0);
            VM0; BARR;
            STAGE(0, (t + 2) * BK);
            COMPUTE(1);
            VM0; BARR;
        }
        COMPUTE(0);   // tile KT-1

        // fold this chunk into register top-2
        const int cb = colBase + waveN + (lane & 15);
        #pragma unroll
        for (int n = 0; n < 4; n++) {
            const float wq = wsq[cb + n * 16];
            const int ci = cb + n * 16;
            #pragma unroll
            for (int m = 0; m < 4; m++)
                #pragma unroll
                for (int r = 0; r < 4; r++) {
                    float dv = wq - 2.f * acc[m][n][r];
                    top2_insert(dv, ci, V0[m * 4 + r], I0[m * 4 + r],
                                V1[m * 4 + r], I1[m * 4 + r]);
                }
        }
        __syncthreads();   // buf0 reads done before next chunk restages
    }

#undef STAGE
#undef COMPUTE
#undef VM0
#undef BARR

    // cross-lane reduce (once per block) + cross-wave combine
    #pragma unroll
    for (int q = 0; q < 16; q++) {
        float v0 = V0[q], v1 = V1[q];
        int i0 = I0[q], i1 = I1[q];
        #pragma unroll
        for (int mask = 1; mask < 16; mask <<= 1) {
            float w0 = __shfl_xor(v0, mask); int j0 = __shfl_xor(i0, mask);
            float w1 = __shfl_xor(v1, mask); int j1 = __shfl_xor(i1, mask);
            top2_insert(w0, j0, v0, i0, v1, i1);
            top2_insert(w1, j1, v0, i0, v1, i1);
        }
        if ((lane & 15) == 0) {
            int m = q >> 2, r = q & 3;
            int row_local = waveM + m * 16 + (lane >> 4) * 4 + r;
            red[row_local][wid & 1] =
                make_float4(v0, __int_as_float(i0), v1, __int_as_float(i1));
        }
    }
    __syncthreads();
    if (tid < BM) {
        float4 pa = red[tid][0], pb = red[tid][1];
        float v0 = pa.x, v1 = pa.z;
        int i0 = __float_as_int(pa.y), i1 = __float_as_int(pa.w);
        top2_insert(pb.x, __float_as_int(pb.y), v0, i0, v1, i1);
        top2_insert(pb.z, __float_as_int(pb.w), v0, i0, v1, i1);
        partial[(size_t)(rowBase + tid) * gx + bx] =
            make_float4(v0, __int_as_float(i0), v1, __int_as_float(i1));
    }
}

// ---------------------------------------------------------------------------
// Rescue: fp64 rescore of all candidates within MARGIN of approx global min.
// ---------------------------------------------------------------------------
__global__ __launch_bounds__(256) void rescore_kernel(const float* __restrict__ x,
                                                      const float* __restrict__ w,
                                                      const float4* __restrict__ partial,
                                                      float* __restrict__ out, int ng) {
    int wid = threadIdx.x >> 6, lane = threadIdx.x & 63;
    int row = blockIdx.x * 4 + wid;
    __shared__ int s_cnt[4];
    __shared__ int s_cand[4][64];

    const float4* part = partial + (size_t)row * ng;

    float bv = INFINITY;
    for (int c = lane; c < ng; c += 64) bv = fminf(bv, part[c].x);
    #pragma unroll
    for (int mask = 1; mask < 64; mask <<= 1) bv = fminf(bv, __shfl_xor(bv, mask));
    float thr = bv + MARGIN;

    if (lane == 0) s_cnt[wid] = 0;
    __syncthreads();
    for (int c = lane; c < ng; c += 64) {
        float4 p = part[c];
        if (p.x <= thr) {
            int pos = atomicAdd(&s_cnt[wid], 1);
            if (pos < 64) s_cand[wid][pos] = __float_as_int(p.y);
        }
        if (p.z <= thr) {
            int pos = atomicAdd(&s_cnt[wid], 1);
            if (pos < 64) s_cand[wid][pos] = __float_as_int(p.w);
        }
    }
    __syncthreads();
    int cnt = s_cnt[wid]; if (cnt > 64) cnt = 64;

    double bd = INFINITY; int bi = 0x7fffffff;
    for (int c = 0; c < cnt; c++) {
        int idx = s_cand[wid][c];
        const float* wr = w + (size_t)idx * D;
        const float* xr = x + (size_t)row * D;
        double s = 0.0;
        for (int d = lane; d < D; d += 64) {
            double wv = (double)wr[d];
            s += wv * (wv - 2.0 * (double)xr[d]);
        }
        #pragma unroll
        for (int mask = 1; mask < 64; mask <<= 1) s += __shfl_xor(s, mask);
        if (s < bd || (s == bd && idx < bi)) { bd = s; bi = idx; }
    }

    const float4* src = (const float4*)(w + (size_t)bi * D);
    float4* dst = (float4*)(out + (size_t)row * D);
    for (int i = lane; i < D / 4; i += 64) dst[i] = src[i];
}

// ---------------------------------------------------------------------------
extern "C" void kernel_launch(void* const* d_in, const int* in_sizes, int n_in,
                              void* d_out, int out_size, void* d_ws, size_t ws_size,
                              hipStream_t stream) {
    const float* x = (const float*)d_in[0];
    const float* w = (const float*)d_in[1];
    float* out = (float*)d_out;

    const size_t off_xh = 0;
    const size_t off_wh = off_xh + (size_t)BATCH * KP * 2;     // 6,553,600
    const size_t off_wsq = off_wh + (size_t)NPAD * KP * 2;     // +16,384,000
    const size_t off_part = off_wsq + (size_t)NPAD * 4;        // +40,960

    // ws-size ladder: gx=80 (best parallelism) -> 40 -> 20 (known-fitting)
    int gx = 80, cpb = 1;
    if (ws_size < off_part + (size_t)BATCH * 80 * 16) { gx = 40; cpb = 2; }
    if (ws_size < off_part + (size_t)BATCH * 40 * 16) { gx = 20; cpb = 4; }

    unsigned short* xh = (unsigned short*)((char*)d_ws + off_xh);
    unsigned short* wh = (unsigned short*)((char*)d_ws + off_wh);
    float* wsq = (float*)((char*)d_ws + off_wsq);
    float4* partial = (float4*)((char*)d_ws + off_part);

    hipLaunchKernelGGL(convert_x_kernel, dim3(BATCH), dim3(256), 0, stream, x, xh);
    hipLaunchKernelGGL(convert_w_kernel, dim3(NPAD), dim3(256), 0, stream, w, wh, wsq);
    hipLaunchKernelGGL(dist_mfma_kernel, dim3(gx, 32), dim3(256), 0, stream,
                       xh, wh, wsq, partial, gx, cpb);
    hipLaunchKernelGGL(rescore_kernel, dim3(BATCH / 4), dim3(256), 0, stream,
                       x, w, partial, out, gx);
}